// Round 1
// baseline (186.863 us; speedup 1.0000x reference)
//
#include <hip/hip_runtime.h>

// FOFE encoding: out[row, :] = sum_k alpha^(L-1-k) * onehot(char_ids[row, k])
// rows = B*W = 131072, L = 20, VOCAB = 256. Output fp32 = 128 MiB -> write-BW
// bound; floor ~22us at 6.3 TB/s. Headline dur includes ~100us harness
// re-poison (R4 finding), so target total ~= 122us.
//
// R6: drop LDS entirely. R5's per-pair zero->atomicAdd->readback LDS chain
// (~350 dependent cycles/pair, plus bank-conflict serialization on the 40
// random-address LDS atomics) was the store-data producer choke. With
// VOCAB=256 and wave=64, each lane owns vocab slots [4*lane, 4*lane+3] in
// registers. Ids are wave-uniform per row: broadcast each of the 20 ids with
// v_readlane (SGPR result), then branchless compare-select accumulate:
//   per char: 1 readlane + 1 v_cmp (lane match) + 4x {cndmask+add}, with the
//   component gate (id&3) uniform -> scalar pipe.
// ~400 VALU cycles/row * 131072 rows / 1024 SIMDs ~= 21us of VALU that
// overlaps the ~22us store stream. No LDS, no atomics, no barriers, no
// lgkmcnt waits -- stores pace only against HBM.

constexpr int L     = 20;
constexpr int VOCAB = 256;
constexpr int BLOCK = 256;            // 4 waves per block
constexpr int GRID  = 2048;           // 8192 waves total
constexpr int RPW   = 16;             // rows per wave: 8192 * 16 = 131072

__global__ __launch_bounds__(BLOCK) void fofe_kernel(
    const int* __restrict__ char_ids,
    const float* __restrict__ alpha_ptr,
    float* __restrict__ out,
    int n_rows)
{
    const int lane        = threadIdx.x & 63;
    const int wave_id     = (blockIdx.x * BLOCK + (int)threadIdx.x) >> 6;
    const int total_waves = (gridDim.x * blockDim.x) >> 6;

    const float alpha = *alpha_ptr;

    // pw[k] = alpha^(L-1-k); same repeated-multiply fp sequence as the
    // reference's alpha**arange (verified within threshold in prior rounds).
    float pw[L];
    {
        float cur = 1.0f;
        #pragma unroll
        for (int e = 0; e < L; ++e) { pw[(L - 1) - e] = cur; cur *= alpha; }
    }

    float4* out4 = (float4*)out;

    // Outer grid-stride loop runs exactly once at the bench shape.
    for (int base = wave_id * RPW; base < n_rows; base += total_waves * RPW) {

        // ---- Phase 1: issue all 16 row-id loads up front (independent
        // global_load_dword, lanes 0..19 active; exec-masked so the last row
        // never reads past the buffer). No vmem op after this point except
        // the pure store stream.
        int myid[RPW];
        #pragma unroll
        for (int r = 0; r < RPW; ++r) {
            const int row = base + r;
            myid[r] = (lane < L && row < n_rows)
                          ? char_ids[(size_t)row * L + lane] : 0;
        }

        // ---- Phase 2: per row, accumulate this lane's 4 contiguous vocab
        // slots across the 20 chars, then one coalesced global_store_dwordx4
        // (1 KiB per wave per store).
        #pragma unroll
        for (int r = 0; r < RPW; ++r) {
            const int row = base + r;
            if (row < n_rows) {                      // wave-uniform guard
                float4 a = make_float4(0.f, 0.f, 0.f, 0.f);
                #pragma unroll
                for (int k = 0; k < L; ++k) {
                    // id is wave-uniform: readlane -> SGPR.
                    const int id = __builtin_amdgcn_readlane(myid[r], k);
                    const bool m = (lane == (id >> 2));  // divergent: 1 v_cmp
                    const int  c = id & 3;               // uniform: scalar pipe
                    a.x += (m && c == 0) ? pw[k] : 0.f;
                    a.y += (m && c == 1) ? pw[k] : 0.f;
                    a.z += (m && c == 2) ? pw[k] : 0.f;
                    a.w += (m && c == 3) ? pw[k] : 0.f;
                }
                out4[(size_t)row * (VOCAB / 4) + lane] = a;
            }
        }
    }
}

extern "C" void kernel_launch(void* const* d_in, const int* in_sizes, int n_in,
                              void* d_out, int out_size, void* d_ws, size_t ws_size,
                              hipStream_t stream) {
    const int*   char_ids = (const int*)d_in[0];
    const float* alpha    = (const float*)d_in[1];
    float*       out      = (float*)d_out;
    const int    n_rows   = in_sizes[0] / L;   // 131072

    fofe_kernel<<<GRID, BLOCK, 0, stream>>>(char_ids, alpha, out, n_rows);
}

// Round 2
// 169.505 us; speedup vs baseline: 1.1024x; 1.1024x over previous
//
#include <hip/hip_runtime.h>

// FOFE encoding: out[row, :] = sum_k alpha^(L-1-k) * onehot(char_ids[row, k])
// rows = B*W = 131072, L = 20, VOCAB = 256. Output fp32 = 128 MiB -> write-BW
// bound; memory floor ~22us (128 MiB out + 10 MiB in at 6.3 TB/s). Headline
// includes ~163us of harness re-poison fills (2x 512 MiB @ 81us, rocprof R6);
// realistic headline floor ~= 170us.
//
// R6 post-mortem: kernel absent from top-5 (all 81us fills) => < 81us, but
// the (m && c==j) ? pw : 0 formulation compiles to ~10 SALU/char (s_lshr +
// s_and + 4x s_cmp+s_cselect_b64) for the uniform component gate. The CU has
// ONE scalar ALU shared by 4 SIMDs: 512 rows/CU * 20 chars * 10 SALU ~= 102k
// cyc ~= 43us -- the kernel was scalar-pipe bound, not VALU/store bound.
//
// R7: zero SALU in the char loop. Compare the raw id (SGPR via readlane)
// against four precomputed per-lane slot ids 4*lane+j:
//   per component: v_cmp_eq_u32 vcc, s_id, v_sj ; v_cndmask ; v_add  (3 VALU)
//   per char: 1 readlane + 12 VALU, 0 SALU.
// VALU ~= 10240 chars/CU * 13 / 2 instr/cyc ~= 27us, overlapping the ~22us
// store stream. Also: id loads become 5 fully-coalesced global_load_dword
// (320 contiguous dwords per 16-row block, 64/64 lanes active) instead of 16
// lane-masked loads; readlane selects g[(r*20+k)>>6] lane (r*20+k)&63 -- all
// compile-time after full unroll, nothing in scratch.

constexpr int L     = 20;
constexpr int VOCAB = 256;
constexpr int BLOCK = 256;            // 4 waves per block
constexpr int GRID  = 2048;           // 8192 waves total
constexpr int RPW   = 16;             // rows per wave: 8192 * 16 = 131072
constexpr int GDW   = RPW * L / 64;   // 5 dwords of ids per lane per block

__global__ __launch_bounds__(BLOCK) void fofe_kernel(
    const int* __restrict__ char_ids,
    const float* __restrict__ alpha_ptr,
    float* __restrict__ out,
    int n_rows)
{
    const int lane        = threadIdx.x & 63;
    const int wave_id     = (blockIdx.x * BLOCK + (int)threadIdx.x) >> 6;
    const int total_waves = (gridDim.x * blockDim.x) >> 6;

    const float alpha = *alpha_ptr;

    // pw[k] = alpha^(L-1-k); same repeated-multiply fp sequence as the
    // reference's alpha**arange (absmax ~1e-39 in R6 -- exact match).
    float pw[L];
    {
        float cur = 1.0f;
        #pragma unroll
        for (int e = 0; e < L; ++e) { pw[(L - 1) - e] = cur; cur *= alpha; }
    }

    // This lane's four owned vocab slots (VGPRs; compare targets).
    const int s0 = lane * 4;
    const int s1 = s0 + 1;
    const int s2 = s0 + 2;
    const int s3 = s0 + 3;

    float4* out4 = (float4*)out;
    const int total_dw = n_rows * L;

    // Outer grid-stride loop runs exactly once at the bench shape.
    for (int base = wave_id * RPW; base < n_rows; base += total_waves * RPW) {

        // ---- Phase 1: 5 fully-coalesced id loads (320 contiguous dwords =
        // 16 rows x 20 chars). The ONLY vmem reads; all precede any store.
        int g[GDW];
        const int fb = base * L;
        #pragma unroll
        for (int q = 0; q < GDW; ++q) {
            const int d = fb + q * 64 + lane;
            g[q] = (d < total_dw) ? char_ids[d] : 0;
        }

        // ---- Phase 2: per row, branchless pure-VALU accumulate of this
        // lane's 4 slots, then one coalesced global_store_dwordx4 (1 KiB per
        // wave-store). No SALU in the char loop, no LDS, no waits on stores.
        #pragma unroll
        for (int r = 0; r < RPW; ++r) {
            const int row = base + r;
            if (row < n_rows) {                      // wave-uniform guard
                float4 a = make_float4(0.f, 0.f, 0.f, 0.f);
                #pragma unroll
                for (int k = 0; k < L; ++k) {
                    const int d  = r * L + k;        // 0..319, compile-time
                    const int id = __builtin_amdgcn_readlane(g[d >> 6], d & 63);
                    a.x += (id == s0) ? pw[k] : 0.f; // v_cmp+cndmask+add
                    a.y += (id == s1) ? pw[k] : 0.f;
                    a.z += (id == s2) ? pw[k] : 0.f;
                    a.w += (id == s3) ? pw[k] : 0.f;
                }
                out4[(size_t)row * (VOCAB / 4) + lane] = a;
            }
        }
    }
}

extern "C" void kernel_launch(void* const* d_in, const int* in_sizes, int n_in,
                              void* d_out, int out_size, void* d_ws, size_t ws_size,
                              hipStream_t stream) {
    const int*   char_ids = (const int*)d_in[0];
    const float* alpha    = (const float*)d_in[1];
    float*       out      = (float*)d_out;
    const int    n_rows   = in_sizes[0] / L;   // 131072

    fofe_kernel<<<GRID, BLOCK, 0, stream>>>(char_ids, alpha, out, n_rows);
}